// Round 9
// baseline (144.967 us; speedup 1.0000x reference)
//
#include <hip/hip_runtime.h>

typedef short bf16x8 __attribute__((ext_vector_type(8)));
typedef float f32x4 __attribute__((ext_vector_type(4)));

#define AS1 __attribute__((address_space(1)))
#define AS3 __attribute__((address_space(3)))

__device__ __forceinline__ void gload16(const void* g, void* l) {
  __builtin_amdgcn_global_load_lds((const AS1 void*)g, (AS3 void*)l, 16, 0, 0);
}

__device__ __forceinline__ unsigned short f2bf(float f) {
  union { float f; unsigned u; } v; v.f = f;
  unsigned r = v.u + 0x7FFFu + ((v.u >> 16) & 1u);
  return (unsigned short)(r >> 16);
}

// packed f32x2 -> bf16x2 (low = a, high = b), RNE — same rounding as f2bf
__device__ __forceinline__ unsigned cvtpk(float a, float b) {
  unsigned r;
  asm("v_cvt_pk_bf16_f32 %0, %1, %2" : "=v"(r) : "v"(a), "v"(b));
  return r;
}

// NOTE: v_permlane32_swap_b32 deliberately NOT used anywhere. With xx==yy the
// register allocator may coalesce both "+v" operands into ONE register, making
// the swap degenerate (lane ends with only the partner half's value). This was
// the root cause of the round-3/4/5/8 correctness failures. __shfl_xor(.,32)
// is the verified-safe cross-half combine (rounds 6/7 passed with it).

// ---------------- cast fp32 -> bf16, vectorized ----------------
__global__ __launch_bounds__(256) void cast_kernel(const float* __restrict__ in,
                                                   unsigned short* __restrict__ out, int n4) {
  int i = blockIdx.x * blockDim.x + threadIdx.x;
  if (i < n4) {
    float4 v = reinterpret_cast<const float4*>(in)[i];
    ushort4 o; o.x = f2bf(v.x); o.y = f2bf(v.y); o.z = f2bf(v.z); o.w = f2bf(v.w);
    reinterpret_cast<ushort4*>(out)[i] = o;
  }
}

// ---------------- 128x128 tile GEMM, BK=64, swizzled LDS, C = A * B^T ----------------
template<int MODE>
__global__ __launch_bounds__(256) void gemm128(
    const unsigned short* __restrict__ A, const unsigned short* __restrict__ B,
    int K, int N,
    unsigned short* __restrict__ Qh, unsigned short* __restrict__ Kh,
    unsigned short* __restrict__ Vt,
    float* __restrict__ Cf, const float* __restrict__ bias) {
  __shared__ unsigned short Ab[128 * 64];  // 16 KB
  __shared__ unsigned short Bb[128 * 64];  // 16 KB
  const int tid = threadIdx.x, lane = tid & 63, wave = tid >> 6;
  const int l15 = lane & 15, lhi = lane >> 4;
  const int m0 = blockIdx.y * 128, n0 = blockIdx.x * 128;
  const int wr = wave >> 1, wc = wave & 1;

  f32x4 acc[4][4] = {};

  const int srow = tid >> 3;
  const int scol = (((tid & 7) * 16) ^ ((srow & 7) << 4)) >> 1;  // elements
  const unsigned short* aSrc = A + (size_t)(m0 + srow) * K + scol;
  const unsigned short* bSrc = B + (size_t)(n0 + srow) * K + scol;
  char* ldsA = (char*)Ab + wave * 1024;
  char* ldsB = (char*)Bb + wave * 1024;

  const int rswz = (l15 & 7) << 4;

  for (int k0 = 0; k0 < K; k0 += 64) {
    __syncthreads();
#pragma unroll
    for (int i = 0; i < 4; ++i) {
      gload16(aSrc + k0 + (size_t)32 * K * i, ldsA + i * 4096);
      gload16(bSrc + k0 + (size_t)32 * K * i, ldsB + i * 4096);
    }
    __syncthreads();
#pragma unroll
    for (int ks = 0; ks < 2; ++ks) {
      bf16x8 af[4], bfr[4];
#pragma unroll
      for (int mm = 0; mm < 4; ++mm)
        af[mm] = *reinterpret_cast<const bf16x8*>(
            (char*)Ab + (wr * 64 + mm * 16 + l15) * 128 + ((ks * 64 + lhi * 16) ^ rswz));
#pragma unroll
      for (int nn = 0; nn < 4; ++nn)
        bfr[nn] = *reinterpret_cast<const bf16x8*>(
            (char*)Bb + (wc * 64 + nn * 16 + l15) * 128 + ((ks * 64 + lhi * 16) ^ rswz));
#pragma unroll
      for (int mm = 0; mm < 4; ++mm)
#pragma unroll
        for (int nn = 0; nn < 4; ++nn)
          acc[mm][nn] = __builtin_amdgcn_mfma_f32_16x16x32_bf16(af[mm], bfr[nn], acc[mm][nn], 0, 0, 0);
    }
  }

  if (MODE == 0) {
    const int region = (n0 >= 1536) ? 2 : (n0 >= 768 ? 1 : 0);
#pragma unroll
    for (int mm = 0; mm < 4; ++mm) {
      int gm = m0 + wr * 64 + mm * 16 + lhi * 4;
      int bb = gm >> 10, nb = gm & 1023;
#pragma unroll
      for (int nn = 0; nn < 4; ++nn) {
        int gn = n0 + wc * 64 + nn * 16 + l15 - region * 768;
        int d = gn & 63, hh = gn >> 6;
        if (region == 2) {
          ushort4 o;
          o.x = f2bf(acc[mm][nn][0]); o.y = f2bf(acc[mm][nn][1]);
          o.z = f2bf(acc[mm][nn][2]); o.w = f2bf(acc[mm][nn][3]);
          *reinterpret_cast<ushort4*>(&Vt[((size_t)(bb * 12 + hh) * 64 + d) * 1024 + nb]) = o;
        } else {
          unsigned short* dst =
              (region == 0 ? Qh : Kh) + ((size_t)(bb * 12 + hh) * 1024 + nb) * 64 + d;
#pragma unroll
          for (int r = 0; r < 4; ++r) dst[(size_t)r * 64] = f2bf(acc[mm][nn][r]);
        }
      }
    }
  } else {
#pragma unroll
    for (int mm = 0; mm < 4; ++mm) {
      int gm = m0 + wr * 64 + mm * 16 + lhi * 4;
#pragma unroll
      for (int nn = 0; nn < 4; ++nn) {
        int gn = n0 + wc * 64 + nn * 16 + l15;
        float bv = bias[gn];
#pragma unroll
        for (int r = 0; r < 4; ++r)
          Cf[(size_t)(gm + r) * N + gn] = acc[mm][nn][r] + bv;
      }
    }
  }
}

// ---------------- flash attention: K LDS-staged (1 barrier/iter), V direct-from-global ----------------
__global__ __launch_bounds__(256) void attn_kernel(
    const unsigned short* __restrict__ qh, const unsigned short* __restrict__ kh,
    const unsigned short* __restrict__ vt, unsigned short* __restrict__ aout) {
  __shared__ unsigned short KT[2][4096];  // [kv 64][d 64] swizzled, 8KB/buf
  __shared__ unsigned short P[4][2048];   // per-wave 32x64 bf16
  __shared__ float Al[4][32];             // per-wave alpha[q] (rescale)
  __shared__ float Li[4][32];             // per-wave lrun[q] (final norm)

  const int tid = threadIdx.x, lane = tid & 63, wave = tid >> 6;
  const int l15 = lane & 15, lhi = lane >> 4;
  // XCD-locality: all 8 q-tiles of one bh on one XCD (96 % 8 == 0)
  const int bh = blockIdx.x % 96, qt = blockIdx.x / 96;
  const int b = bh / 12, h = bh % 12;
  const float c1 = 0.125f * 1.44269504088896340736f;  // scale * log2(e)

  // K staging: thread t -> tile row t>>3 (+32), chunk t&7, inverse-swizzled src col
  const int srow = tid >> 3;
  const int scol = (((tid & 7) * 16) ^ ((srow & 7) << 4)) >> 1;
  const unsigned short* kS0 = kh + ((size_t)bh * 1024 + srow) * 64 + scol;
  const unsigned short* kS1 = kS0 + (size_t)32 * 64;
  char* kD = (char*)&KT[0][0] + wave * 1024;

  // V fragments direct from global (round-1/7-verified addressing):
  // vf0[dt] = V^T[d = dt*16 + l15][kv0 + lhi*8 + j], vf1: +32
  const unsigned short* vgbase = vt + ((size_t)bh * 64 + l15) * 1024 + lhi * 8;

  // Q fragments: 32 rows per wave
  const int qw0 = qt * 128 + wave * 32;
  bf16x8 qf[2][2];
#pragma unroll
  for (int rb = 0; rb < 2; ++rb)
#pragma unroll
    for (int ks = 0; ks < 2; ++ks)
      qf[rb][ks] = *reinterpret_cast<const bf16x8*>(
          qh + ((size_t)bh * 1024 + qw0 + rb * 16 + l15) * 64 + ks * 32 + lhi * 8);

  f32x4 oacc[2][4] = {};
  float mrun[2] = {-1e30f, -1e30f};
  float lsum[2] = {0.f, 0.f};  // per-lane partial (reduced in epilogue)

  const int rswz = (l15 & 7) << 4;
  const int fo0 = l15 * 128 + ((lhi * 16) ^ rswz);
  const int fo1 = l15 * 128 + ((64 + lhi * 16) ^ rswz);
  unsigned short* pl = &P[wave][0];

  // prologue: stage K tile 0 into buf 0
  gload16(kS0, kD); gload16(kS1, kD + 4096);

  for (int kt = 0; kt < 16; ++kt) {
    const int cur = kt & 1;
    const int kv0 = kt * 64;
    asm volatile("s_waitcnt vmcnt(0)" ::: "memory");  // K tile kt landed
    __builtin_amdgcn_s_barrier();

    // prefetch next K tile into other buffer (safe: cur^1 fully consumed before this barrier)
    if (kt < 15) {
      char* kd = kD + (cur ^ 1) * 8192;
      gload16(kS0 + (size_t)(kv0 + 64) * 64, kd);
      gload16(kS1 + (size_t)(kv0 + 64) * 64, kd + 4096);
    }

    // issue V loads for this tile (L2-resident; consumed in PV ~full iter later)
    bf16x8 vf0[4], vf1[4];
#pragma unroll
    for (int dt = 0; dt < 4; ++dt) {
      const unsigned short* vp = vgbase + (size_t)(dt * 16) * 1024 + kv0;
      vf0[dt] = *reinterpret_cast<const bf16x8*>(vp);
      vf1[dt] = *reinterpret_cast<const bf16x8*>(vp + 32);
    }

    const char* kb = (const char*)&KT[cur][0];

    // QK^T swapped: s[rb][nt] = D[kv = nt*16 + lhi*4 + r][q = rb*16 + l15]
    f32x4 s[2][4] = {};
#pragma unroll
    for (int nt = 0; nt < 4; ++nt) {
      bf16x8 kf0 = *reinterpret_cast<const bf16x8*>(kb + nt * 2048 + fo0);
      bf16x8 kf1 = *reinterpret_cast<const bf16x8*>(kb + nt * 2048 + fo1);
#pragma unroll
      for (int rb = 0; rb < 2; ++rb) {
        s[rb][nt] = __builtin_amdgcn_mfma_f32_16x16x32_bf16(kf0, qf[rb][0], s[rb][nt], 0, 0, 0);
        s[rb][nt] = __builtin_amdgcn_mfma_f32_16x16x32_bf16(kf1, qf[rb][1], s[rb][nt], 0, 0, 0);
      }
    }

    // ---- softmax: local tree + shfl_xor(16) + shfl_xor(32) (verified combine) ----
    float mt[2];
#pragma unroll
    for (int rb = 0; rb < 2; ++rb) {
      float a0 = fmaxf(fmaxf(s[rb][0][0], s[rb][0][1]), fmaxf(s[rb][0][2], s[rb][0][3]));
      float a1 = fmaxf(fmaxf(s[rb][1][0], s[rb][1][1]), fmaxf(s[rb][1][2], s[rb][1][3]));
      float a2 = fmaxf(fmaxf(s[rb][2][0], s[rb][2][1]), fmaxf(s[rb][2][2], s[rb][2][3]));
      float a3 = fmaxf(fmaxf(s[rb][3][0], s[rb][3][1]), fmaxf(s[rb][3][2], s[rb][3][3]));
      float rm = fmaxf(fmaxf(a0, a1), fmaxf(a2, a3));
      rm = fmaxf(rm, __shfl_xor(rm, 16, 64));
      rm = fmaxf(rm, __shfl_xor(rm, 32, 64));
      mt[rb] = rm * c1;
    }

    // T13 defer-max
    bool ok = (mt[0] - mrun[0] <= 8.f) && (mt[1] - mrun[1] <= 8.f);
    if (!__all(ok)) {
      float al[2];
#pragma unroll
      for (int rb = 0; rb < 2; ++rb) {
        float mn = fmaxf(mrun[rb], mt[rb]);
        al[rb] = __builtin_amdgcn_exp2f(mrun[rb] - mn);
        mrun[rb] = mn;
        lsum[rb] *= al[rb];  // per-lane partial scales by the (q-uniform) alpha
      }
      if (lhi == 0) { Al[wave][l15] = al[0]; Al[wave][16 + l15] = al[1]; }
#pragma unroll
      for (int rb = 0; rb < 2; ++rb) {
        f32x4 av = *reinterpret_cast<const f32x4*>(&Al[wave][rb * 16 + lhi * 4]);
#pragma unroll
        for (int dt = 0; dt < 4; ++dt)
#pragma unroll
          for (int r = 0; r < 4; ++r) oacc[rb][dt][r] *= av[r];
      }
    }

#pragma unroll
    for (int rb = 0; rb < 2; ++rb) {
#pragma unroll
      for (int nt = 0; nt < 4; ++nt)
#pragma unroll
        for (int r = 0; r < 4; ++r)
          s[rb][nt][r] = __builtin_amdgcn_exp2f(__builtin_fmaf(s[rb][nt][r], c1, -mrun[rb]));

      // per-lane partial sum only (cross-lane reduce deferred to epilogue)
      float b0 = (s[rb][0][0] + s[rb][0][1]) + (s[rb][0][2] + s[rb][0][3]);
      float b1 = (s[rb][1][0] + s[rb][1][1]) + (s[rb][1][2] + s[rb][1][3]);
      float b2 = (s[rb][2][0] + s[rb][2][1]) + (s[rb][2][2] + s[rb][2][3]);
      float b3 = (s[rb][3][0] + s[rb][3][1]) + (s[rb][3][2] + s[rb][3][3]);
      lsum[rb] += (b0 + b1) + (b2 + b3);
    }

    // ---- P -> swizzled LDS (wave-private), packed b64 writes ----
#pragma unroll
    for (int rb = 0; rb < 2; ++rb)
#pragma unroll
      for (int nt = 0; nt < 4; ++nt) {
        uint2 wv;
        wv.x = cvtpk(s[rb][nt][0], s[rb][nt][1]);
        wv.y = cvtpk(s[rb][nt][2], s[rb][nt][3]);
        *reinterpret_cast<uint2*>(
            (char*)pl + rb * 2048 + l15 * 128 + ((nt * 32 + lhi * 8) ^ rswz)) = wv;
      }

    bf16x8 paf[2][2];
#pragma unroll
    for (int rb = 0; rb < 2; ++rb) {
      paf[rb][0] = *reinterpret_cast<const bf16x8*>((char*)pl + rb * 2048 + fo0);
      paf[rb][1] = *reinterpret_cast<const bf16x8*>((char*)pl + rb * 2048 + fo1);
    }

#pragma unroll
    for (int dt = 0; dt < 4; ++dt) {
#pragma unroll
      for (int rb = 0; rb < 2; ++rb) {
        oacc[rb][dt] = __builtin_amdgcn_mfma_f32_16x16x32_bf16(paf[rb][0], vf0[dt], oacc[rb][dt], 0, 0, 0);
        oacc[rb][dt] = __builtin_amdgcn_mfma_f32_16x16x32_bf16(paf[rb][1], vf1[dt], oacc[rb][dt], 0, 0, 0);
      }
    }
  }

  // ---- epilogue: reduce per-lane partial sums across lhi, then normalize ----
  float ls[2];
#pragma unroll
  for (int rb = 0; rb < 2; ++rb) {
    float v = lsum[rb];
    v += __shfl_xor(v, 16, 64);
    v += __shfl_xor(v, 32, 64);
    ls[rb] = v;
  }
  if (lhi == 0) { Li[wave][l15] = ls[0]; Li[wave][16 + l15] = ls[1]; }
#pragma unroll
  for (int rb = 0; rb < 2; ++rb) {
    f32x4 lv = *reinterpret_cast<const f32x4*>(&Li[wave][rb * 16 + lhi * 4]);
    float inv[4];
#pragma unroll
    for (int r = 0; r < 4; ++r) inv[r] = 1.f / lv[r];
#pragma unroll
    for (int dt = 0; dt < 4; ++dt)
#pragma unroll
      for (int r = 0; r < 4; ++r) {
        int n = qw0 + rb * 16 + lhi * 4 + r;
        int d = dt * 16 + l15;
        aout[((size_t)(b * 1024 + n)) * 768 + h * 64 + d] = f2bf(oacc[rb][dt][r] * inv[r]);
      }
  }
}

extern "C" void kernel_launch(void* const* d_in, const int* in_sizes, int n_in,
                              void* d_out, int out_size, void* d_ws, size_t ws_size,
                              hipStream_t stream) {
  const float* x      = (const float*)d_in[0];
  const float* qkv_w  = (const float*)d_in[1];
  const float* proj_w = (const float*)d_in[2];
  const float* proj_b = (const float*)d_in[3];
  float* out = (float*)d_out;

  char* ws = (char*)d_ws;
  unsigned short* xb     = (unsigned short*)(ws);              // 8192x768 bf16
  unsigned short* wqkvb  = (unsigned short*)(ws + 12582912);   // 2304x768
  unsigned short* wprojb = (unsigned short*)(ws + 16121856);   // 768x768
  unsigned short* qhb    = (unsigned short*)(ws + 17301504);   // [96][1024][64]
  unsigned short* khb    = (unsigned short*)(ws + 29884416);   // [96][1024][64]
  unsigned short* vtb    = (unsigned short*)(ws + 42467328);   // [96][64][1024]
  unsigned short* aob    = (unsigned short*)(ws + 55050240);   // 8192x768

  cast_kernel<<<6144, 256, 0, stream>>>(x, xb, 1572864);
  cast_kernel<<<1728, 256, 0, stream>>>(qkv_w, wqkvb, 442368);
  cast_kernel<<<576, 256, 0, stream>>>(proj_w, wprojb, 147456);

  dim3 g1(2304 / 128, 8192 / 128);
  gemm128<0><<<g1, 256, 0, stream>>>(xb, wqkvb, 768, 2304, qhb, khb, vtb, nullptr, nullptr);

  attn_kernel<<<96 * 8, 256, 0, stream>>>(qhb, khb, vtb, aob);

  dim3 g2(768 / 128, 8192 / 128);
  gemm128<1><<<g2, 256, 0, stream>>>(aob, wprojb, 768, 768, nullptr, nullptr, nullptr, out, proj_b);
}